// Round 2
// 1074.107 us; speedup vs baseline: 1.9771x; 1.9771x over previous
//
#include <hip/hip_runtime.h>
#include <math.h>

#define BB 8
#define CC 64
#define NCAP 16
#define HH 96
#define WW 96
#define PP (HH*WW)      // 9216
#define BNN (BB*NCAP)   // 128
#define EPSN 1e-5f

typedef short short8 __attribute__((ext_vector_type(8)));
typedef unsigned short u16x8 __attribute__((ext_vector_type(8)));
typedef float float4v __attribute__((ext_vector_type(4)));

__device__ __forceinline__ float bf2f(unsigned short u){
  union{unsigned int i; float f;} x; x.i = ((unsigned int)u)<<16; return x.f;
}
__device__ __forceinline__ unsigned short f2bf(float f){
  union{float f; unsigned int i;} x; x.f=f;
  unsigned int r = x.i + 0x7fffu + ((x.i>>16)&1u);
  return (unsigned short)(r>>16);
}
__device__ __forceinline__ float4v mfma16(short8 a, short8 b, float4v c){
  return __builtin_amdgcn_mfma_f32_16x16x32_bf16(a, b, c, 0, 0, 0);
}

// ---------------- block reduction helpers (256-thread blocks) ----------------
__device__ __forceinline__ float blkred_sum(float v, float* red4){
  int tid = threadIdx.x; int lane = tid & 63, wv = tid >> 6;
  #pragma unroll
  for (int off=32; off>0; off>>=1) v += __shfl_down(v, off, 64);
  __syncthreads();
  if (lane == 0) red4[wv] = v;
  __syncthreads();
  return red4[0] + red4[1] + red4[2] + red4[3];
}
__device__ __forceinline__ float blkred_max(float v, float* red4){
  int tid = threadIdx.x; int lane = tid & 63, wv = tid >> 6;
  #pragma unroll
  for (int off=32; off>0; off>>=1) v = fmaxf(v, __shfl_down(v, off, 64));
  __syncthreads();
  if (lane == 0) red4[wv] = v;
  __syncthreads();
  return fmaxf(fmaxf(red4[0], red4[1]), fmaxf(red4[2], red4[3]));
}

// ---------------- KPRE: transpose tg[b][c][p] fp32 -> tgt[b][p][c] bf16 ----------------
__global__ void kpre_tgt(const float* __restrict__ tg, unsigned short* __restrict__ tgt){
  int b = blockIdx.x/36, pc = blockIdx.x - (blockIdx.x/36)*36;
  int p = pc*256 + threadIdx.x;
  unsigned short vals[CC];
  #pragma unroll 8
  for (int c=0;c<CC;c++) vals[c] = f2bf(tg[((size_t)b*CC + c)*PP + p]);
  u16x8* dst = (u16x8*)&tgt[((size_t)b*PP + p)*CC];
  #pragma unroll
  for (int j=0;j<8;j++){
    u16x8 v;
    #pragma unroll
    for (int e=0;e<8;e++) v[e] = vals[j*8+e];
    dst[j] = v;
  }
}

// ---------------- KW: conv1 weights [o][c][k9] fp32 -> Wt[k9][o][c] bf16 ----------------
__global__ void kw_bf16(const float* __restrict__ w1, unsigned short* __restrict__ Wt){
  int i = blockIdx.x*256 + threadIdx.x;   // 36864 exactly
  int o = i/576; int rem = i - o*576; int c = rem/9; int tap = rem - c*9;
  Wt[(tap*CC + o)*CC + c] = f2bf(w1[i]);
}

// ---------------- K0: per-(b,c) sums of sr (t) and tg (S1,S2) ----------------
__global__ void k0_colstats(const float* __restrict__ sr, const float* __restrict__ tg,
                            float* __restrict__ t, float* __restrict__ S1, float* __restrict__ S2){
  int row = blockIdx.x;                 // b*CC + c, 512 rows
  const float* srp = sr + (size_t)row * PP;
  const float* tgp = tg + (size_t)row * PP;
  float s0=0.f, a1=0.f, a2=0.f;
  for (int p = threadIdx.x; p < PP; p += 256){
    s0 += srp[p];
    float v = tgp[p];
    a1 += v; a2 += v*v;
  }
  __shared__ float red4[4];
  s0 = blkred_sum(s0, red4);
  a1 = blkred_sum(a1, red4);
  a2 = blkred_sum(a2, red4);
  if (threadIdx.x == 0){ t[row]=s0; S1[row]=a1; S2[row]=a2; }
}

// ------- K1/K5: op = W_n.vec + biasmul*w_b ; opn ; u = W_n^T.opn ; bu --------
__global__ void k_update(const float* __restrict__ Wm, const float* __restrict__ wb,
                         const float* __restrict__ vec, float biasmul, int perB,
                         float* __restrict__ opv, float* __restrict__ uv, float* __restrict__ bu){
  int bn = blockIdx.x; int n = bn & (NCAP-1); int b = bn >> 4;
  int c = threadIdx.x;                  // 64 threads
  __shared__ float Wsh[CC*65];
  __shared__ float vsh[CC];
  __shared__ float opsh[CC];
  vsh[c] = perB ? vec[b*CC + c] : vec[bn*CC + c];
  const float* Wn = Wm + (size_t)n*CC*CC;
  for (int i=c;i<CC*CC;i+=64){ int r=i>>6, k=i&63; Wsh[r*65+k]=Wn[i]; }
  __syncthreads();
  float acc = biasmul * wb[n*CC + c];
  #pragma unroll 8
  for (int k=0;k<CC;k++) acc += Wsh[c*65+k]*vsh[k];
  opv[bn*CC+c] = acc;
  float ss = acc*acc;
  #pragma unroll
  for (int off=32;off>0;off>>=1) ss += __shfl_down(ss, off, 64);
  ss = __shfl(ss, 0, 64);
  float inv = 1.0f / fmaxf(sqrtf(ss), 1e-12f);
  opsh[c] = acc * inv;
  __syncthreads();
  float uacc = 0.f;
  #pragma unroll 8
  for (int k=0;k<CC;k++) uacc += opsh[k] * Wsh[k*65+c];
  uv[bn*CC+c] = uacc;
  float bb = opsh[c]*wb[n*CC+c];
  #pragma unroll
  for (int off=32;off>0;off>>=1) bb += __shfl_down(bb, off, 64);
  if (c==0) bu[bn] = bb;
}

// ------- K2F: fused d-pass + softmax partials + weighted partial sums -------
// grid 8*72, block 128 (one 128-pixel chunk per block).
// d[b,n,p] = u.sr_p + bu; per-block (m,z) partials; and
// prt[b,pc,n,c] = sum_{p in chunk} exp(d[n,p]-m_blk[n]) * sr[c,p]
// dbuf written only when writed!=0 (last routing iteration, for k6).
__global__ __launch_bounds__(128) void k2f_dpass(
    const float* __restrict__ sr, const float* __restrict__ uv,
    const float* __restrict__ bu, float* __restrict__ dbuf,
    float* __restrict__ partm, float* __restrict__ partz,
    float* __restrict__ prt, int writed){
  int b = blockIdx.x / 72; int pc = blockIdx.x - b*72;
  int tid = threadIdx.x;
  int p = pc*128 + tid;
  __shared__ float ush[NCAP][CC];
  __shared__ float bush[NCAP];
  __shared__ float msh[NCAP];
  __shared__ float wsh[NCAP*132];   // d then exp-weights, stride 132 (16B-aligned)
  __shared__ float srsh[CC*132];    // sr tile [c][p], stride 132
  for (int i=tid;i<NCAP*CC;i+=128) ush[i>>6][i&63] = uv[b*NCAP*CC + i];
  if (tid < NCAP) bush[tid] = bu[b*NCAP+tid];
  __syncthreads();
  float acc[NCAP];
  #pragma unroll
  for (int n=0;n<NCAP;n++) acc[n]=bush[n];
  #pragma unroll 4
  for (int c=0;c<CC;c++){
    float v = sr[((size_t)b*CC + c)*PP + p];
    srsh[c*132+tid] = v;
    #pragma unroll
    for (int n=0;n<NCAP;n++) acc[n] += ush[n][c]*v;
  }
  #pragma unroll
  for (int n=0;n<NCAP;n++){
    wsh[n*132+tid] = acc[n];
    if (writed) dbuf[((size_t)(b*NCAP+n))*PP + p] = acc[n];
  }
  __syncthreads();
  // softmax partials: 16 teams of 8 lanes; team n reduces its 128 d-values
  {
    int n = tid >> 3, seg = tid & 7;
    float m = -1e30f;
    #pragma unroll
    for (int i=0;i<16;i++) m = fmaxf(m, wsh[n*132+seg*16+i]);
    #pragma unroll
    for (int off=1; off<8; off<<=1) m = fmaxf(m, __shfl_xor(m, off, 64));
    float z = 0.f;
    #pragma unroll
    for (int i=0;i<16;i++) z += __expf(wsh[n*132+seg*16+i] - m);
    #pragma unroll
    for (int off=1; off<8; off<<=1) z += __shfl_xor(z, off, 64);
    if (seg == 0){
      partm[(b*NCAP + n)*72 + pc] = m;
      partz[(b*NCAP + n)*72 + pc] = z;
      msh[n] = m;
    }
  }
  __syncthreads();
  #pragma unroll
  for (int n=0;n<NCAP;n++) wsh[n*132+tid] = __expf(wsh[n*132+tid]-msh[n]);
  __syncthreads();
  // weighted partial sums: wave-half handles 8 capsules, lane = channel
  {
    int c = tid & 63, half = tid >> 6;
    float acc8[8];
    #pragma unroll
    for (int i=0;i<8;i++) acc8[i]=0.f;
    const float4* sp = (const float4*)&srsh[c*132];
    #pragma unroll 4
    for (int k=0;k<32;k++){
      float4 sv = sp[k];
      #pragma unroll
      for (int i=0;i<8;i++){
        float4 wv = *(const float4*)&wsh[(half*8+i)*132+4*k];
        acc8[i] += wv.x*sv.x + wv.y*sv.y + wv.z*sv.z + wv.w*sv.w;
      }
    }
    float* pb = prt + (((size_t)b*72+pc)*NCAP + half*8)*CC + c;
    #pragma unroll
    for (int i=0;i<8;i++) pb[(size_t)i*CC] = acc8[i];
  }
}

// ---------------- K3b: combine per-block softmax partials (72 chunks) ----------------
__global__ void k3b_combine(const float* __restrict__ partm, const float* __restrict__ partz,
                            float* __restrict__ mrow, float* __restrict__ zrow){
  int bn = blockIdx.x; int t = threadIdx.x;   // 64 threads
  float m1 = partm[bn*72 + t];
  float m2 = (t < 8) ? partm[bn*72 + 64 + t] : -1e30f;
  float mm = fmaxf(m1, m2);
  #pragma unroll
  for (int off=32;off>0;off>>=1) mm = fmaxf(mm, __shfl_xor(mm, off, 64));
  float z = partz[bn*72 + t]*__expf(m1 - mm);
  if (t < 8) z += partz[bn*72 + 64 + t]*__expf(m2 - mm);
  #pragma unroll
  for (int off=32;off>0;off>>=1) z += __shfl_xor(z, off, 64);
  if (t==0){ mrow[bn]=mm; zrow[bn]=z; }
}

// ---------------- K4c: fold weighted partials -> r[b,n,c] ----------------
__global__ void k4c_combine(const float* __restrict__ prt, const float* __restrict__ partm,
                            const float* __restrict__ mrow, const float* __restrict__ zrow,
                            float* __restrict__ rv){
  int bn = blockIdx.x; int b = bn >> 4, n = bn & (NCAP-1);
  int c = threadIdx.x;                  // 64 threads
  float M = mrow[bn], invZ = 1.0f/zrow[bn];
  float s = 0.f;
  #pragma unroll 8
  for (int pc=0;pc<72;pc++){
    float w = __expf(partm[bn*72+pc] - M);
    s += prt[(((size_t)b*72+pc)*NCAP + n)*CC + c] * w;
  }
  rv[bn*CC+c] = s*invZ;
}

// ---------------- K6: write final cof output ----------------
__global__ void k6_cofout(const float* __restrict__ dbuf, const float* __restrict__ mrow,
                          const float* __restrict__ zrow, float* __restrict__ cof){
  int bn = blockIdx.y;
  int p = blockIdx.x*256 + threadIdx.x;
  float m=mrow[bn], invz=1.0f/zrow[bn];
  cof[(size_t)bn*PP+p] = __expf(dbuf[(size_t)bn*PP+p]-m)*invz;
}

// ---------------- K7: GN1 closed-form affine (A,D per b,n,c) + zero partials ----------------
__global__ void k7_gn1(const float* __restrict__ S1, const float* __restrict__ S2,
                       const float* __restrict__ opv, const float* __restrict__ g1,
                       const float* __restrict__ b1, float* __restrict__ Aaff,
                       float* __restrict__ Daff, float* __restrict__ gn2s,
                       float* __restrict__ gn2q, float* __restrict__ in2s,
                       float* __restrict__ in2q){
  int bn = blockIdx.x; int b = bn >> 4;
  int c = threadIdx.x;                  // 64 threads
  __shared__ float e1[CC], e2[CC], mu[16], ri[16];
  float op = opv[bn*CC+c];
  float s1 = S1[b*CC+c], s2 = S2[b*CC+c];
  e1[c] = s1 + (float)PP*op;
  e2[c] = s2 + 2.0f*op*s1 + (float)PP*op*op;
  __syncthreads();
  if (c < 16){
    float m  = (e1[4*c]+e1[4*c+1]+e1[4*c+2]+e1[4*c+3])*(1.0f/(4.0f*PP));
    float qq = (e2[4*c]+e2[4*c+1]+e2[4*c+2]+e2[4*c+3])*(1.0f/(4.0f*PP));
    mu[c]=m; ri[c]=rsqrtf(qq-m*m+EPSN);
    gn2s[bn*16+c]=0.f; gn2q[bn*16+c]=0.f;
  }
  if (bn==0){ in2s[c]=0.f; in2s[CC+c]=0.f; in2q[c]=0.f; in2q[CC+c]=0.f; }
  __syncthreads();
  int g = c>>2;
  float A = ri[g]*g1[c];
  Aaff[bn*CC+c]=A;
  Daff[bn*CC+c]=(op-mu[g])*A + b1[c];
}

// ---------------- K8: conv1 via bf16 MFMA implicit GEMM ----------------
__global__ __launch_bounds__(256) void k8_conv1_mfma(
    const unsigned short* __restrict__ tgt, const unsigned short* __restrict__ Wt,
    const float* __restrict__ c1b, const float* __restrict__ Aaff,
    const float* __restrict__ Daff, unsigned short* __restrict__ y1b,
    float* __restrict__ gn2s, float* __restrict__ gn2q){
  int blk = blockIdx.x;
  int bn = blk/36, tt = blk - bn*36;
  int ty = tt/3, tx = tt - ty*3;
  int y0 = ty*8, x0 = tx*32;
  int b = bn >> 4;
  int tid = threadIdx.x, w = tid>>6, lane = tid&63, quad = lane>>4, col16 = lane&15;

  __shared__ unsigned short xh[10*34*72];   // [row][col][ch(72 pad)]
  __shared__ float Ash[CC], Dsh[CC];
  if (tid < CC){ Ash[tid]=Aaff[bn*CC+tid]; Dsh[tid]=Daff[bn*CC+tid]; }
  __syncthreads();

  const unsigned short* tgb = tgt + (size_t)b*PP*CC;
  for (int task = tid; task < 2720; task += 256){   // 340 pixels x 8 ch-octets
    int j = task & 7, pi = task >> 3;
    int row = pi/34, col = pi - row*34;
    int gy = y0 + row - 1, gx = x0 + col - 1;
    u16x8 ov;
    if ((unsigned)gy < (unsigned)HH && (unsigned)gx < (unsigned)WW){
      u16x8 iv = *(const u16x8*)(tgb + ((size_t)(gy*WW+gx))*CC + j*8);
      #pragma unroll
      for (int e=0;e<8;e++){
        float f = bf2f(iv[e]);
        f = fmaxf(Ash[j*8+e]*f + Dsh[j*8+e], 0.f);
        ov[e] = f2bf(f);
      }
    } else {
      #pragma unroll
      for (int e=0;e<8;e++) ov[e]=0;
    }
    *(u16x8*)&xh[(row*34+col)*72 + j*8] = ov;
  }
  __syncthreads();

  float4v acc[4][4];
  #pragma unroll
  for (int mt=0;mt<4;mt++)
    #pragma unroll
    for (int nt=0;nt<4;nt++)
      #pragma unroll
      for (int e=0;e<4;e++) acc[mt][nt][e]=0.f;

  const unsigned short* xb0 = &xh[((2*w + 1)*34 + 1 + col16)*72 + quad*8];
  const unsigned short* wbase = Wt + (size_t)(col16*CC + quad*8);
  #pragma unroll
  for (int tap=0; tap<9; ++tap){
    const int dy = tap/3 - 1, dx = tap - (tap/3)*3 - 1;
    const int toff = (dy*34 + dx)*72;
    #pragma unroll
    for (int chunk=0; chunk<2; ++chunk){
      short8 a[4];
      #pragma unroll
      for (int mt=0;mt<4;mt++)
        a[mt] = *(const short8*)(wbase + tap*4096 + mt*1024 + chunk*32);
      short8 bf[4];
      #pragma unroll
      for (int nt=0;nt<4;nt++){
        int ri = nt>>1, h = nt&1;
        bf[nt] = *(const short8*)(xb0 + toff + ri*(34*72) + h*(16*72) + chunk*32);
      }
      #pragma unroll
      for (int mt=0;mt<4;mt++)
        #pragma unroll
        for (int nt=0;nt<4;nt++)
          acc[mt][nt] = mfma16(a[mt], bf[nt], acc[mt][nt]);
    }
  }

  unsigned short* ybn = y1b + (size_t)bn*CC*PP;
  #pragma unroll
  for (int mt=0;mt<4;mt++){
    float gs=0.f, gq=0.f;
    #pragma unroll
    for (int nt=0;nt<4;nt++){
      int ri = nt>>1, h = nt&1;
      int y = y0 + 2*w + ri, x = x0 + h*16 + col16;
      #pragma unroll
      for (int e=0;e<4;e++){
        int o = mt*16 + quad*4 + e;
        float v = acc[mt][nt][e] + c1b[o];
        ybn[(size_t)o*PP + y*WW + x] = f2bf(v);
        gs += v; gq += v*v;
      }
    }
    #pragma unroll
    for (int off=1; off<16; off<<=1){
      gs += __shfl_xor(gs, off, 64);
      gq += __shfl_xor(gq, off, 64);
    }
    if (col16==0){
      atomicAdd(&gn2s[bn*16 + mt*4 + quad], gs);
      atomicAdd(&gn2q[bn*16 + mt*4 + quad], gq);
    }
  }
}

// ---------------- K9: finalize GN2 per-channel affine ----------------
__global__ void k9_gn2fin(const float* __restrict__ gn2s, const float* __restrict__ gn2q,
                          const float* __restrict__ g2c, const float* __restrict__ b2c,
                          float* __restrict__ A2, float* __restrict__ D2){
  int bn = blockIdx.x; int o = threadIdx.x;   // 64 threads
  int g = o>>2;
  float m = gn2s[bn*16+g]*(1.0f/(4.0f*PP));
  float q = gn2q[bn*16+g]*(1.0f/(4.0f*PP));
  float ri = rsqrtf(q - m*m + EPSN);
  float A = ri * g2c[o];
  A2[bn*CC+o] = A;
  D2[bn*CC+o] = b2c[o] - m*A;
}

// ---------------- K10: conv2 64->1 3x3, bf16 y1 input, fused GN2-affine+ReLU -> msk ----------------
__global__ void k10_conv2(const unsigned short* __restrict__ y1b, const float* __restrict__ w2,
                          const float* __restrict__ b2, const float* __restrict__ A2,
                          const float* __restrict__ D2, float* __restrict__ mskout){
  int blk=blockIdx.x; int bn=blk/36; int tt=blk-bn*36;
  int y0=(tt/3)*8, x0=(tt%3)*32;
  int tid=threadIdx.x;
  int xi=tid&31, yi=tid>>5;
  __shared__ float xs[8][10][35];
  __shared__ float wsh2[CC*9];
  __shared__ float Ash[CC], Dsh[CC];
  for (int i=tid;i<CC*9;i+=256) wsh2[i]=w2[i];
  if (tid<CC){ Ash[tid]=A2[bn*CC+tid]; Dsh[tid]=D2[bn*CC+tid]; }
  float acc=0.f;
  const unsigned short* yb = y1b + (size_t)bn*CC*PP;
  #pragma unroll 1
  for (int cc2=0;cc2<CC;cc2+=8){
    __syncthreads();
    for (int i=tid;i<8*10*34;i+=256){
      int col=i%34; int rest=i/34; int row=rest%10; int ci=rest/10;
      int gy=y0+row-1, gx=x0+col-1;
      int cgl=cc2+ci;
      float v=0.f;
      if (gy>=0&&gy<HH&&gx>=0&&gx<WW)
        v=fmaxf(0.f, Ash[cgl]*bf2f(yb[(size_t)cgl*PP+gy*WW+gx])+Dsh[cgl]);
      xs[ci][row][col]=v;
    }
    __syncthreads();
    #pragma unroll 1
    for (int ci=0;ci<8;ci++){
      int cgl=cc2+ci;
      #pragma unroll
      for (int kh=0;kh<3;kh++){
        #pragma unroll
        for (int kw=0;kw<3;kw++)
          acc += wsh2[cgl*9+kh*3+kw]*xs[ci][yi+kh][xi+kw];
      }
    }
  }
  acc += b2[0];
  mskout[(size_t)bn*PP+(size_t)(y0+yi)*WW+(x0+xi)] = acc;
}

// ---------------- K11: per-(b,n) msk stats: IN1 affine + center-of-mass loss ----------------
__global__ void k11_mskstats(const float* __restrict__ msk, const float* __restrict__ in1g,
                             const float* __restrict__ in1b, float* __restrict__ in1A,
                             float* __restrict__ in1D, float* __restrict__ lossbn){
  int bn = blockIdx.x; int n = bn & (NCAP-1);
  const float* mp = msk + (size_t)bn*PP;
  __shared__ float red4[4];
  float mx=-1e30f, s=0.f, q=0.f;
  for (int p=threadIdx.x;p<PP;p+=256){ float v=mp[p]; mx=fmaxf(mx,v); s+=v; q+=v*v; }
  mx = blkred_max(mx, red4);
  s  = blkred_sum(s, red4);
  q  = blkred_sum(q, red4);
  float z=0.f, sy=0.f, sx=0.f, syy=0.f, sxx=0.f;
  for (int p=threadIdx.x;p<PP;p+=256){
    float e = __expf(mp[p]-mx);
    int py = p/WW, px = p - py*WW;
    float iy = -1.0f + py*(2.0f/95.0f);
    float ix = -1.0f + px*(2.0f/95.0f);
    z+=e; sy+=e*iy; sx+=e*ix; syy+=e*iy*iy; sxx+=e*ix*ix;
  }
  z=blkred_sum(z,red4); sy=blkred_sum(sy,red4); sx=blkred_sum(sx,red4);
  syy=blkred_sum(syy,red4); sxx=blkred_sum(sxx,red4);
  if (threadIdx.x==0){
    float invz=1.0f/z;
    float ey=sy*invz, ex=sx*invz;
    lossbn[bn]=(syy*invz-ey*ey)+(sxx*invz-ex*ex);
    float mu=s*(1.0f/PP), var=q*(1.0f/PP)-mu*mu;
    float A=rsqrtf(var+EPSN)*in1g[n];
    in1A[bn]=A; in1D[bn]=in1b[n]-mu*A;
  }
}

// ---------------- K12: centr_loss = mean(lossbn) ----------------
__global__ void k12_loss(const float* __restrict__ lossbn, float* __restrict__ lossout){
  int tid=threadIdx.x;   // 128 threads
  float v = lossbn[tid];
  #pragma unroll
  for (int off=32;off>0;off>>=1) v += __shfl_down(v,off,64);
  __shared__ float r2[2];
  if ((tid&63)==0) r2[tid>>6]=v;
  __syncthreads();
  if (tid==0) lossout[0] = (r2[0]+r2[1]) * (1.0f/128.0f);
}

// ---------------- K13: gen-block stage 1: g2 = c3.relu(IN1(msk)) + IN2 partials ----------------
__global__ void k13_gen1(const float* __restrict__ msk, const float* __restrict__ in1A,
                         const float* __restrict__ in1D, const float* __restrict__ c3w,
                         const float* __restrict__ c3b, float* __restrict__ g2,
                         float* __restrict__ in2s, float* __restrict__ in2q){
  int b = blockIdx.x/36; int pc = blockIdx.x - b*36;
  int p = pc*256+threadIdx.x;
  __shared__ float wsh[NCAP*NCAP];
  __shared__ float Ash[NCAP], Dsh[NCAP], bsh[NCAP];
  if (threadIdx.x < NCAP*NCAP) wsh[threadIdx.x] = c3w[threadIdx.x];
  if (threadIdx.x < NCAP){
    Ash[threadIdx.x]=in1A[b*NCAP+threadIdx.x];
    Dsh[threadIdx.x]=in1D[b*NCAP+threadIdx.x];
    bsh[threadIdx.x]=c3b[threadIdx.x];
  }
  __syncthreads();
  float h[NCAP];
  #pragma unroll
  for (int n=0;n<NCAP;n++)
    h[n] = fmaxf(0.f, Ash[n]*msk[(size_t)(b*NCAP+n)*PP+p] + Dsh[n]);
  float g[NCAP];
  #pragma unroll
  for (int o=0;o<NCAP;o++){
    float a = bsh[o];
    #pragma unroll
    for (int n=0;n<NCAP;n++) a += wsh[o*NCAP+n]*h[n];
    g[o]=a;
    g2[(size_t)(b*NCAP+o)*PP+p]=a;
  }
  int lane = threadIdx.x & 63;
  #pragma unroll
  for (int o=0;o<NCAP;o++){
    float a=g[o], q=g[o]*g[o];
    #pragma unroll
    for (int off=32;off>0;off>>=1){ a+=__shfl_down(a,off,64); q+=__shfl_down(q,off,64); }
    if (lane==0){ atomicAdd(&in2s[b*NCAP+o],a); atomicAdd(&in2q[b*NCAP+o],q); }
  }
}

// ---------------- K14: finalize IN2 affine ----------------
__global__ void k14_in2fin(const float* __restrict__ in2s, const float* __restrict__ in2q,
                           const float* __restrict__ g, const float* __restrict__ bb,
                           float* __restrict__ in2A, float* __restrict__ in2D){
  int i=threadIdx.x;   // 128 = b*16+o
  int o=i&15;
  float m=in2s[i]*(1.0f/PP), q=in2q[i]*(1.0f/PP);
  float A=rsqrtf(q-m*m+EPSN)*g[o];
  in2A[i]=A; in2D[i]=bb[o]-m*A;
}

// ---------------- K15: rec = sigmoid(c4.relu(IN2(g2))) ----------------
__global__ void k15_rec(const float* __restrict__ g2, const float* __restrict__ in2A,
                        const float* __restrict__ in2D, const float* __restrict__ c4w,
                        const float* __restrict__ c4b, float* __restrict__ rec){
  int b = blockIdx.x/36; int pc = blockIdx.x - b*36;
  int p = pc*256+threadIdx.x;
  __shared__ float wsh[3*NCAP], Ash[NCAP], Dsh[NCAP], bsh[3];
  if (threadIdx.x<3*NCAP) wsh[threadIdx.x]=c4w[threadIdx.x];
  if (threadIdx.x<NCAP){ Ash[threadIdx.x]=in2A[b*NCAP+threadIdx.x]; Dsh[threadIdx.x]=in2D[b*NCAP+threadIdx.x]; }
  if (threadIdx.x<3) bsh[threadIdx.x]=c4b[threadIdx.x];
  __syncthreads();
  float h[NCAP];
  #pragma unroll
  for (int o=0;o<NCAP;o++)
    h[o]=fmaxf(0.f, Ash[o]*g2[(size_t)(b*NCAP+o)*PP+p]+Dsh[o]);
  #pragma unroll
  for (int j=0;j<3;j++){
    float z=bsh[j];
    #pragma unroll
    for (int o=0;o<NCAP;o++) z += wsh[j*NCAP+o]*h[o];
    rec[(size_t)(b*3+j)*PP+p] = 1.0f/(1.0f+__expf(-z));
  }
}

// ---------------- K16: op_out[b,n,c,p] = op[b,n,c]*msk[b,n,p] ----------------
__global__ void k16_opout(const float* __restrict__ opv, const float* __restrict__ msk,
                          float* __restrict__ out){
  int bn = blockIdx.x / 9; int pt = blockIdx.x - bn*9;
  int base = pt*1024;
  __shared__ float ms[1024];
  __shared__ float opl[CC];
  for (int i=threadIdx.x;i<1024;i+=256) ms[i]=msk[(size_t)bn*PP+base+i];
  if (threadIdx.x<CC) opl[threadIdx.x]=opv[bn*CC+threadIdx.x];
  __syncthreads();
  float4 mv = ((const float4*)ms)[threadIdx.x];
  float* obase = out + (size_t)bn*CC*PP + base;
  #pragma unroll 4
  for (int c=0;c<CC;c++){
    float ov = opl[c];
    ((float4*)(obase + (size_t)c*PP))[threadIdx.x] = make_float4(ov*mv.x,ov*mv.y,ov*mv.z,ov*mv.w);
  }
}

// =======================================================================
extern "C" void kernel_launch(void* const* d_in, const int* in_sizes, int n_in,
                              void* d_out, int out_size, void* d_ws, size_t ws_size,
                              hipStream_t stream){
  const float* sr   = (const float*)d_in[0];
  const float* tg   = (const float*)d_in[1];
  const float* w_w  = (const float*)d_in[2];
  const float* w_b  = (const float*)d_in[3];
  const float* gn1g = (const float*)d_in[4];
  const float* gn1b = (const float*)d_in[5];
  const float* c1w  = (const float*)d_in[6];
  const float* c1b  = (const float*)d_in[7];
  const float* gn2g = (const float*)d_in[8];
  const float* gn2b = (const float*)d_in[9];
  const float* c2w  = (const float*)d_in[10];
  const float* c2b  = (const float*)d_in[11];
  const float* in1g = (const float*)d_in[12];
  const float* in1b = (const float*)d_in[13];
  const float* c3w  = (const float*)d_in[14];
  const float* c3b  = (const float*)d_in[15];
  const float* in2g = (const float*)d_in[16];
  const float* in2b = (const float*)d_in[17];
  const float* c4w  = (const float*)d_in[18];
  const float* c4b  = (const float*)d_in[19];
  float* out = (float*)d_out;
  float* ws  = (float*)d_ws;

  // workspace layout (floats) — byte-identical footprint to the proven round-0 layout
  float* t_   = ws + 0;
  float* S1   = ws + 512;
  float* S2   = ws + 1024;
  float* opv  = ws + 1536;
  float* uv   = ws + 9728;
  float* bu   = ws + 17920;
  float* mrow = ws + 18048;
  float* zrow = ws + 18176;
  float* rv   = ws + 18304;
  float* Aaff = ws + 26496;
  float* Daff = ws + 34688;
  float* gn2s = ws + 42880;
  float* gn2q = ws + 44928;
  float* A2   = ws + 46976;
  float* D2   = ws + 55168;
  float* in1A = ws + 63360;
  float* in1D = ws + 63488;
  float* lossbn = ws + 63616;
  float* in2s = ws + 63744;
  float* in2q = ws + 63872;
  float* in2A = ws + 64000;
  float* in2D = ws + 64128;
  float* dbuf = ws + 65536;              // 1,179,648 floats
  float* g2   = ws + 65536 + 1179648;    // 1,179,648 floats

  // d_out region reuse (everything here is overwritten by k16/mask/rec/etc later):
  // y1 (bf16) first, then tgt, Wt, routing partial-sums prt, and softmax partials.
  unsigned short* y1b = (unsigned short*)d_out;                                  // 150,994,944 B
  unsigned short* tgt = (unsigned short*)((char*)d_out + 150994944);             // 9,437,184 B
  unsigned short* Wt  = (unsigned short*)((char*)d_out + 160432128);             // 73,728 B
  float* prt   = (float*)((char*)d_out + 160505856);                             // 2,359,296 B (8*72*16*64 f32)
  float* partm = (float*)((char*)d_out + 162865152);                             // 36,864 B (128 bn x 72)
  float* partz = (float*)((char*)d_out + 162902016);                             // 36,864 B
  // ends at 162,938,880 B << 301,989,888 B (op_out region), overwritten by k16 last
  float* mskout  = out + 75497472;
  float* recout  = out + 76677120;
  float* lossout = out + 76898304;
  float* cofout  = out + 76898305;

  kpre_tgt<<<BB*36, 256, 0, stream>>>(tg, tgt);
  kw_bf16<<<144, 256, 0, stream>>>(c1w, Wt);
  k0_colstats<<<BB*CC, 256, 0, stream>>>(sr, tg, t_, S1, S2);
  k_update<<<BNN, 64, 0, stream>>>(w_w, w_b, t_, (float)PP, 1, opv, uv, bu);
  for (int it=0; it<3; ++it){
    k2f_dpass<<<BB*72, 128, 0, stream>>>(sr, uv, bu, dbuf, partm, partz, prt, it==2 ? 1 : 0);
    k3b_combine<<<BNN, 64, 0, stream>>>(partm, partz, mrow, zrow);
    k4c_combine<<<BNN, 64, 0, stream>>>(prt, partm, mrow, zrow, rv);
    k_update<<<BNN, 64, 0, stream>>>(w_w, w_b, rv, 1.0f, 0, opv, uv, bu);
  }
  k6_cofout<<<dim3(36, BNN), 256, 0, stream>>>(dbuf, mrow, zrow, cofout);
  k7_gn1<<<BNN, 64, 0, stream>>>(S1, S2, opv, gn1g, gn1b, Aaff, Daff, gn2s, gn2q, in2s, in2q);
  k8_conv1_mfma<<<BNN*36, 256, 0, stream>>>(tgt, Wt, c1b, Aaff, Daff, y1b, gn2s, gn2q);
  k9_gn2fin<<<BNN, 64, 0, stream>>>(gn2s, gn2q, gn2g, gn2b, A2, D2);
  k10_conv2<<<BNN*36, 256, 0, stream>>>(y1b, c2w, c2b, A2, D2, mskout);
  k11_mskstats<<<BNN, 256, 0, stream>>>(mskout, in1g, in1b, in1A, in1D, lossbn);
  k12_loss<<<1, 128, 0, stream>>>(lossbn, lossout);
  k13_gen1<<<BB*36, 256, 0, stream>>>(mskout, in1A, in1D, c3w, c3b, g2, in2s, in2q);
  k14_in2fin<<<1, 128, 0, stream>>>(in2s, in2q, in2g, in2b, in2A, in2D);
  k15_rec<<<BB*36, 256, 0, stream>>>(g2, in2A, in2D, c4w, c4b, recout);
  k16_opout<<<BNN*9, 256, 0, stream>>>(opv, mskout, out);
}

// Round 4
// 1036.771 us; speedup vs baseline: 2.0484x; 1.0360x over previous
//
#include <hip/hip_runtime.h>
#include <math.h>

#define BB 8
#define CC 64
#define NCAP 16
#define HH 96
#define WW 96
#define PP (HH*WW)      // 9216
#define BNN (BB*NCAP)   // 128
#define EPSN 1e-5f

typedef short short8 __attribute__((ext_vector_type(8)));
typedef unsigned short u16x8 __attribute__((ext_vector_type(8)));
typedef unsigned short u16x4 __attribute__((ext_vector_type(4)));
typedef float float4v __attribute__((ext_vector_type(4)));

__device__ __forceinline__ float bf2f(unsigned short u){
  union{unsigned int i; float f;} x; x.i = ((unsigned int)u)<<16; return x.f;
}
__device__ __forceinline__ unsigned short f2bf(float f){
  union{float f; unsigned int i;} x; x.f=f;
  unsigned int r = x.i + 0x7fffu + ((x.i>>16)&1u);
  return (unsigned short)(r>>16);
}
__device__ __forceinline__ float4v mfma16(short8 a, short8 b, float4v c){
  return __builtin_amdgcn_mfma_f32_16x16x32_bf16(a, b, c, 0, 0, 0);
}

// ---------------- block reduction helpers (256-thread blocks) ----------------
__device__ __forceinline__ float blkred_sum(float v, float* red4){
  int tid = threadIdx.x; int lane = tid & 63, wv = tid >> 6;
  #pragma unroll
  for (int off=32; off>0; off>>=1) v += __shfl_down(v, off, 64);
  __syncthreads();
  if (lane == 0) red4[wv] = v;
  __syncthreads();
  return red4[0] + red4[1] + red4[2] + red4[3];
}
__device__ __forceinline__ float blkred_max(float v, float* red4){
  int tid = threadIdx.x; int lane = tid & 63, wv = tid >> 6;
  #pragma unroll
  for (int off=32; off>0; off>>=1) v = fmaxf(v, __shfl_down(v, off, 64));
  __syncthreads();
  if (lane == 0) red4[wv] = v;
  __syncthreads();
  return fmaxf(fmaxf(red4[0], red4[1]), fmaxf(red4[2], red4[3]));
}

// ---------------- KPRE: transpose tg[b][c][p] fp32 -> tgt[b][p][c] bf16 ----------------
__global__ void kpre_tgt(const float* __restrict__ tg, unsigned short* __restrict__ tgt){
  int b = blockIdx.x/36, pc = blockIdx.x - (blockIdx.x/36)*36;
  int p = pc*256 + threadIdx.x;
  unsigned short vals[CC];
  #pragma unroll 8
  for (int c=0;c<CC;c++) vals[c] = f2bf(tg[((size_t)b*CC + c)*PP + p]);
  u16x8* dst = (u16x8*)&tgt[((size_t)b*PP + p)*CC];
  #pragma unroll
  for (int j=0;j<8;j++){
    u16x8 v;
    #pragma unroll
    for (int e=0;e<8;e++) v[e] = vals[j*8+e];
    dst[j] = v;
  }
}

// ---------------- KW: conv1 weights [o][c][k9] fp32 -> Wt[k9][o][c] bf16 ----------------
__global__ void kw_bf16(const float* __restrict__ w1, unsigned short* __restrict__ Wt){
  int i = blockIdx.x*256 + threadIdx.x;   // 36864 exactly
  int o = i/576; int rem = i - o*576; int c = rem/9; int tap = rem - c*9;
  Wt[(tap*CC + o)*CC + c] = f2bf(w1[i]);
}

// ---------------- K0: per-(b,c) sums of sr (t) and tg (S1,S2) ----------------
__global__ void k0_colstats(const float* __restrict__ sr, const float* __restrict__ tg,
                            float* __restrict__ t, float* __restrict__ S1, float* __restrict__ S2){
  int row = blockIdx.x;                 // b*CC + c, 512 rows
  const float* srp = sr + (size_t)row * PP;
  const float* tgp = tg + (size_t)row * PP;
  float s0=0.f, a1=0.f, a2=0.f;
  for (int p = threadIdx.x; p < PP; p += 256){
    s0 += srp[p];
    float v = tgp[p];
    a1 += v; a2 += v*v;
  }
  __shared__ float red4[4];
  s0 = blkred_sum(s0, red4);
  a1 = blkred_sum(a1, red4);
  a2 = blkred_sum(a2, red4);
  if (threadIdx.x == 0){ t[row]=s0; S1[row]=a1; S2[row]=a2; }
}

// ------- K1/K5: op = W_n.vec + biasmul*w_b ; opn ; u = W_n^T.opn ; bu --------
__global__ void k_update(const float* __restrict__ Wm, const float* __restrict__ wb,
                         const float* __restrict__ vec, float biasmul, int perB,
                         float* __restrict__ opv, float* __restrict__ uv, float* __restrict__ bu){
  int bn = blockIdx.x; int n = bn & (NCAP-1); int b = bn >> 4;
  int c = threadIdx.x;                  // 64 threads
  __shared__ float Wsh[CC*65];
  __shared__ float vsh[CC];
  __shared__ float opsh[CC];
  vsh[c] = perB ? vec[b*CC + c] : vec[bn*CC + c];
  const float* Wn = Wm + (size_t)n*CC*CC;
  for (int i=c;i<CC*CC;i+=64){ int r=i>>6, k=i&63; Wsh[r*65+k]=Wn[i]; }
  __syncthreads();
  float acc = biasmul * wb[n*CC + c];
  #pragma unroll 8
  for (int k=0;k<CC;k++) acc += Wsh[c*65+k]*vsh[k];
  opv[bn*CC+c] = acc;
  float ss = acc*acc;
  #pragma unroll
  for (int off=32;off>0;off>>=1) ss += __shfl_down(ss, off, 64);
  ss = __shfl(ss, 0, 64);
  float inv = 1.0f / fmaxf(sqrtf(ss), 1e-12f);
  opsh[c] = acc * inv;
  __syncthreads();
  float uacc = 0.f;
  #pragma unroll 8
  for (int k=0;k<CC;k++) uacc += opsh[k] * Wsh[k*65+c];
  uv[bn*CC+c] = uacc;
  float bb = opsh[c]*wb[n*CC+c];
  #pragma unroll
  for (int off=32;off>0;off>>=1) bb += __shfl_down(bb, off, 64);
  if (c==0) bu[bn] = bb;
}

// ------- K2F: fused d-pass + softmax partials + weighted partial sums -------
__global__ __launch_bounds__(128) void k2f_dpass(
    const float* __restrict__ sr, const float* __restrict__ uv,
    const float* __restrict__ bu, float* __restrict__ dbuf,
    float* __restrict__ partm, float* __restrict__ partz,
    float* __restrict__ prt, int writed){
  int b = blockIdx.x / 72; int pc = blockIdx.x - b*72;
  int tid = threadIdx.x;
  int p = pc*128 + tid;
  __shared__ float ush[NCAP][CC];
  __shared__ float bush[NCAP];
  __shared__ float msh[NCAP];
  __shared__ float wsh[NCAP*132];   // d then exp-weights, stride 132 (16B-aligned)
  __shared__ float srsh[CC*132];    // sr tile [c][p], stride 132
  for (int i=tid;i<NCAP*CC;i+=128) ush[i>>6][i&63] = uv[b*NCAP*CC + i];
  if (tid < NCAP) bush[tid] = bu[b*NCAP+tid];
  __syncthreads();
  float acc[NCAP];
  #pragma unroll
  for (int n=0;n<NCAP;n++) acc[n]=bush[n];
  #pragma unroll 4
  for (int c=0;c<CC;c++){
    float v = sr[((size_t)b*CC + c)*PP + p];
    srsh[c*132+tid] = v;
    #pragma unroll
    for (int n=0;n<NCAP;n++) acc[n] += ush[n][c]*v;
  }
  #pragma unroll
  for (int n=0;n<NCAP;n++){
    wsh[n*132+tid] = acc[n];
    if (writed) dbuf[((size_t)(b*NCAP+n))*PP + p] = acc[n];
  }
  __syncthreads();
  // softmax partials: 16 teams of 8 lanes; team n reduces its 128 d-values
  {
    int n = tid >> 3, seg = tid & 7;
    float m = -1e30f;
    #pragma unroll
    for (int i=0;i<16;i++) m = fmaxf(m, wsh[n*132+seg*16+i]);
    #pragma unroll
    for (int off=1; off<8; off<<=1) m = fmaxf(m, __shfl_xor(m, off, 64));
    float z = 0.f;
    #pragma unroll
    for (int i=0;i<16;i++) z += __expf(wsh[n*132+seg*16+i] - m);
    #pragma unroll
    for (int off=1; off<8; off<<=1) z += __shfl_xor(z, off, 64);
    if (seg == 0){
      partm[(b*NCAP + n)*72 + pc] = m;
      partz[(b*NCAP + n)*72 + pc] = z;
      msh[n] = m;
    }
  }
  __syncthreads();
  #pragma unroll
  for (int n=0;n<NCAP;n++) wsh[n*132+tid] = __expf(wsh[n*132+tid]-msh[n]);
  __syncthreads();
  // weighted partial sums: wave-half handles 8 capsules, lane = channel
  {
    int c = tid & 63, half = tid >> 6;
    float acc8[8];
    #pragma unroll
    for (int i=0;i<8;i++) acc8[i]=0.f;
    const float4* sp = (const float4*)&srsh[c*132];
    #pragma unroll 4
    for (int k=0;k<32;k++){
      float4 sv = sp[k];
      #pragma unroll
      for (int i=0;i<8;i++){
        float4 wv = *(const float4*)&wsh[(half*8+i)*132+4*k];
        acc8[i] += wv.x*sv.x + wv.y*sv.y + wv.z*sv.z + wv.w*sv.w;
      }
    }
    float* pb = prt + (((size_t)b*72+pc)*NCAP + half*8)*CC + c;
    #pragma unroll
    for (int i=0;i<8;i++) pb[(size_t)i*CC] = acc8[i];
  }
}

// ---------------- K3b: combine per-block softmax partials (72 chunks) ----------------
__global__ void k3b_combine(const float* __restrict__ partm, const float* __restrict__ partz,
                            float* __restrict__ mrow, float* __restrict__ zrow){
  int bn = blockIdx.x; int t = threadIdx.x;   // 64 threads
  float m1 = partm[bn*72 + t];
  float m2 = (t < 8) ? partm[bn*72 + 64 + t] : -1e30f;
  float mm = fmaxf(m1, m2);
  #pragma unroll
  for (int off=32;off>0;off>>=1) mm = fmaxf(mm, __shfl_xor(mm, off, 64));
  float z = partz[bn*72 + t]*__expf(m1 - mm);
  if (t < 8) z += partz[bn*72 + 64 + t]*__expf(m2 - mm);
  #pragma unroll
  for (int off=32;off>0;off>>=1) z += __shfl_xor(z, off, 64);
  if (t==0){ mrow[bn]=mm; zrow[bn]=z; }
}

// ---------------- K4c: fold weighted partials -> r[b,n,c] ----------------
__global__ void k4c_combine(const float* __restrict__ prt, const float* __restrict__ partm,
                            const float* __restrict__ mrow, const float* __restrict__ zrow,
                            float* __restrict__ rv){
  int bn = blockIdx.x; int b = bn >> 4, n = bn & (NCAP-1);
  int c = threadIdx.x;                  // 64 threads
  float M = mrow[bn], invZ = 1.0f/zrow[bn];
  float s = 0.f;
  #pragma unroll 8
  for (int pc=0;pc<72;pc++){
    float w = __expf(partm[bn*72+pc] - M);
    s += prt[(((size_t)b*72+pc)*NCAP + n)*CC + c] * w;
  }
  rv[bn*CC+c] = s*invZ;
}

// ---------------- K6: write final cof output ----------------
__global__ void k6_cofout(const float* __restrict__ dbuf, const float* __restrict__ mrow,
                          const float* __restrict__ zrow, float* __restrict__ cof){
  int bn = blockIdx.y;
  int p = blockIdx.x*256 + threadIdx.x;
  float m=mrow[bn], invz=1.0f/zrow[bn];
  cof[(size_t)bn*PP+p] = __expf(dbuf[(size_t)bn*PP+p]-m)*invz;
}

// ---------------- K7: GN1 closed-form affine (A,D per b,n,c) + zero partials ----------------
__global__ void k7_gn1(const float* __restrict__ S1, const float* __restrict__ S2,
                       const float* __restrict__ opv, const float* __restrict__ g1,
                       const float* __restrict__ b1, float* __restrict__ Aaff,
                       float* __restrict__ Daff, float* __restrict__ gn2s,
                       float* __restrict__ gn2q, float* __restrict__ in2s,
                       float* __restrict__ in2q){
  int bn = blockIdx.x; int b = bn >> 4;
  int c = threadIdx.x;                  // 64 threads
  __shared__ float e1[CC], e2[CC], mu[16], ri[16];
  float op = opv[bn*CC+c];
  float s1 = S1[b*CC+c], s2 = S2[b*CC+c];
  e1[c] = s1 + (float)PP*op;
  e2[c] = s2 + 2.0f*op*s1 + (float)PP*op*op;
  __syncthreads();
  if (c < 16){
    float m  = (e1[4*c]+e1[4*c+1]+e1[4*c+2]+e1[4*c+3])*(1.0f/(4.0f*PP));
    float qq = (e2[4*c]+e2[4*c+1]+e2[4*c+2]+e2[4*c+3])*(1.0f/(4.0f*PP));
    mu[c]=m; ri[c]=rsqrtf(qq-m*m+EPSN);
    gn2s[bn*16+c]=0.f; gn2q[bn*16+c]=0.f;
  }
  if (bn==0){ in2s[c]=0.f; in2s[CC+c]=0.f; in2q[c]=0.f; in2q[CC+c]=0.f; }
  __syncthreads();
  int g = c>>2;
  float A = ri[g]*g1[c];
  Aaff[bn*CC+c]=A;
  Daff[bn*CC+c]=(op-mu[g])*A + b1[c];
}

// ---------------- K8: conv1 via bf16 MFMA implicit GEMM ----------------
// y1 output layout is PIXEL-MAJOR: y1[bn][p][o] bf16 (o contiguous).
__global__ __launch_bounds__(256, 3) void k8_conv1_mfma(
    const unsigned short* __restrict__ tgt, const unsigned short* __restrict__ Wt,
    const float* __restrict__ c1b, const float* __restrict__ Aaff,
    const float* __restrict__ Daff, unsigned short* __restrict__ y1b,
    float* __restrict__ gn2s, float* __restrict__ gn2q){
  int blk = blockIdx.x;
  int bn = blk/36, tt = blk - bn*36;
  int ty = tt/3, tx = tt - ty*3;
  int y0 = ty*8, x0 = tx*32;
  int b = bn >> 4;
  int tid = threadIdx.x, w = tid>>6, lane = tid&63, quad = lane>>4, col16 = lane&15;

  __shared__ unsigned short xh[10*34*72];   // [row][col][ch(72 pad)]
  __shared__ float Ash[CC], Dsh[CC];
  if (tid < CC){ Ash[tid]=Aaff[bn*CC+tid]; Dsh[tid]=Daff[bn*CC+tid]; }
  __syncthreads();

  const unsigned short* tgb = tgt + (size_t)b*PP*CC;
  for (int task = tid; task < 2720; task += 256){   // 340 pixels x 8 ch-octets
    int j = task & 7, pi = task >> 3;
    int row = pi/34, col = pi - row*34;
    int gy = y0 + row - 1, gx = x0 + col - 1;
    u16x8 ov;
    if ((unsigned)gy < (unsigned)HH && (unsigned)gx < (unsigned)WW){
      u16x8 iv = *(const u16x8*)(tgb + ((size_t)(gy*WW+gx))*CC + j*8);
      #pragma unroll
      for (int e=0;e<8;e++){
        float f = bf2f(iv[e]);
        f = fmaxf(Ash[j*8+e]*f + Dsh[j*8+e], 0.f);
        ov[e] = f2bf(f);
      }
    } else {
      #pragma unroll
      for (int e=0;e<8;e++) ov[e]=0;
    }
    *(u16x8*)&xh[(row*34+col)*72 + j*8] = ov;
  }
  __syncthreads();

  float4v acc[4][4];
  #pragma unroll
  for (int mt=0;mt<4;mt++)
    #pragma unroll
    for (int nt=0;nt<4;nt++)
      #pragma unroll
      for (int e=0;e<4;e++) acc[mt][nt][e]=0.f;

  const unsigned short* xb0 = &xh[((2*w + 1)*34 + 1 + col16)*72 + quad*8];
  const unsigned short* wbase = Wt + (size_t)(col16*CC + quad*8);

  // 1-deep software pipeline over the 18 K-steps (9 taps x 2 ch-chunks)
  short8 a_c[4], b_c[4];
  {
    const int toff0 = ((0/3 - 1)*34 + (0%3) - 1)*72;
    #pragma unroll
    for (int mt=0;mt<4;mt++) a_c[mt] = *(const short8*)(wbase + 0*4096 + mt*1024);
    #pragma unroll
    for (int nt=0;nt<4;nt++){
      int ri = nt>>1, h = nt&1;
      b_c[nt] = *(const short8*)(xb0 + toff0 + ri*2448 + h*1152);
    }
  }
  #pragma unroll
  for (int s=0; s<18; ++s){
    short8 a_n[4], b_n[4];
    if (s < 17){
      const int s1 = s+1, tap1 = s1>>1, ch1 = s1&1;
      const int toff1 = ((tap1/3 - 1)*34 + (tap1%3) - 1)*72;
      #pragma unroll
      for (int mt=0;mt<4;mt++)
        a_n[mt] = *(const short8*)(wbase + tap1*4096 + mt*1024 + ch1*32);
      #pragma unroll
      for (int nt=0;nt<4;nt++){
        int ri = nt>>1, h = nt&1;
        b_n[nt] = *(const short8*)(xb0 + toff1 + ri*2448 + h*1152 + ch1*32);
      }
    }
    #pragma unroll
    for (int mt=0;mt<4;mt++)
      #pragma unroll
      for (int nt=0;nt<4;nt++)
        acc[mt][nt] = mfma16(a_c[mt], b_c[nt], acc[mt][nt]);
    if (s < 17){
      #pragma unroll
      for (int i=0;i<4;i++){ a_c[i]=a_n[i]; b_c[i]=b_n[i]; }
    }
  }

  // epilogue: +bias, coalesced u16x4 bf16 stores to [p][o] layout, GN2 partials
  unsigned short* ybn = y1b + (size_t)bn*PP*CC;
  #pragma unroll
  for (int mt=0;mt<4;mt++){
    float gs=0.f, gq=0.f;
    #pragma unroll
    for (int nt=0;nt<4;nt++){
      int ri = nt>>1, h = nt&1;
      int y = y0 + 2*w + ri, x = x0 + h*16 + col16;
      u16x4 pv;
      #pragma unroll
      for (int e=0;e<4;e++){
        int o = mt*16 + quad*4 + e;
        float v = acc[mt][nt][e] + c1b[o];
        pv[e] = f2bf(v);
        gs += v; gq += v*v;
      }
      *(u16x4*)&ybn[(size_t)(y*WW + x)*CC + mt*16 + quad*4] = pv;
    }
    #pragma unroll
    for (int off=1; off<16; off<<=1){
      gs += __shfl_xor(gs, off, 64);
      gq += __shfl_xor(gq, off, 64);
    }
    if (col16==0){
      atomicAdd(&gn2s[bn*16 + mt*4 + quad], gs);
      atomicAdd(&gn2q[bn*16 + mt*4 + quad], gq);
    }
  }
}

// ---------------- K9: finalize GN2 per-channel affine ----------------
__global__ void k9_gn2fin(const float* __restrict__ gn2s, const float* __restrict__ gn2q,
                          const float* __restrict__ g2c, const float* __restrict__ b2c,
                          float* __restrict__ A2, float* __restrict__ D2){
  int bn = blockIdx.x; int o = threadIdx.x;   // 64 threads
  int g = o>>2;
  float m = gn2s[bn*16+g]*(1.0f/(4.0f*PP));
  float q = gn2q[bn*16+g]*(1.0f/(4.0f*PP));
  float ri = rsqrtf(q - m*m + EPSN);
  float A = ri * g2c[o];
  A2[bn*CC+o] = A;
  D2[bn*CC+o] = b2c[o] - m*A;
}

// ---------------- K10: conv2 64->1 3x3 from pixel-major bf16 y1 ----------------
__global__ __launch_bounds__(256) void k10_conv2(
    const unsigned short* __restrict__ y1b, const float* __restrict__ w2,
    const float* __restrict__ b2, const float* __restrict__ A2,
    const float* __restrict__ D2, float* __restrict__ mskout){
  int blk=blockIdx.x; int bn=blk/36; int tt=blk-bn*36;
  int y0=(tt/3)*8, x0=(tt%3)*32;
  int tid=threadIdx.x;
  __shared__ unsigned short xh2[10*34*72];   // [row][col][ch(72 pad)] raw bf16 y1
  __shared__ float wsh2[CC*9];
  __shared__ float Ash[CC], Dsh[CC];
  for (int i=tid;i<CC*9;i+=256) wsh2[i]=w2[i];
  if (tid<CC){ Ash[tid]=A2[bn*CC+tid]; Dsh[tid]=D2[bn*CC+tid]; }

  const unsigned short* yb = y1b + (size_t)bn*PP*CC;
  for (int task=tid; task<2720; task+=256){   // 340 pixels x 8 ch-octets
    int j = task & 7, pi = task >> 3;
    int row = pi/34, col = pi - row*34;
    int gy = y0 + row - 1, gx = x0 + col - 1;
    u16x8 iv;
    if ((unsigned)gy < (unsigned)HH && (unsigned)gx < (unsigned)WW){
      iv = *(const u16x8*)(yb + ((size_t)(gy*WW+gx))*CC + j*8);
    } else {
      #pragma unroll
      for (int e=0;e<8;e++) iv[e]=0;
    }
    *(u16x8*)&xh2[(row*34+col)*72 + j*8] = iv;
  }
  __syncthreads();

  int xi = tid&31, yi = tid>>5;
  float acc = 0.f;
  for (int t=0; t<9; ++t){
    int kh = t/3, kw = t - kh*3;
    int gy2 = y0 + yi + kh - 1, gx2 = x0 + xi + kw - 1;
    if ((unsigned)gy2 < (unsigned)HH && (unsigned)gx2 < (unsigned)WW){
      const unsigned short* px = &xh2[((yi+kh)*34 + xi+kw)*72];
      #pragma unroll
      for (int oct=0; oct<8; ++oct){
        u16x8 v = *(const u16x8*)(px + oct*8);
        #pragma unroll
        for (int e=0;e<8;e++){
          int c = oct*8 + e;
          float xv = fmaxf(Ash[c]*bf2f(v[e]) + Dsh[c], 0.f);
          acc += wsh2[c*9 + t] * xv;
        }
      }
    }
  }
  acc += b2[0];
  mskout[(size_t)bn*PP + (size_t)(y0+yi)*WW + (x0+xi)] = acc;
}

// ---------------- K11: per-(b,n) msk stats: IN1 affine + center-of-mass loss ----------------
__global__ void k11_mskstats(const float* __restrict__ msk, const float* __restrict__ in1g,
                             const float* __restrict__ in1b, float* __restrict__ in1A,
                             float* __restrict__ in1D, float* __restrict__ lossbn){
  int bn = blockIdx.x; int n = bn & (NCAP-1);
  const float* mp = msk + (size_t)bn*PP;
  __shared__ float red4[4];
  float mx=-1e30f, s=0.f, q=0.f;
  for (int p=threadIdx.x;p<PP;p+=256){ float v=mp[p]; mx=fmaxf(mx,v); s+=v; q+=v*v; }
  mx = blkred_max(mx, red4);
  s  = blkred_sum(s, red4);
  q  = blkred_sum(q, red4);
  float z=0.f, sy=0.f, sx=0.f, syy=0.f, sxx=0.f;
  for (int p=threadIdx.x;p<PP;p+=256){
    float e = __expf(mp[p]-mx);
    int py = p/WW, px = p - py*WW;
    float iy = -1.0f + py*(2.0f/95.0f);
    float ix = -1.0f + px*(2.0f/95.0f);
    z+=e; sy+=e*iy; sx+=e*ix; syy+=e*iy*iy; sxx+=e*ix*ix;
  }
  z=blkred_sum(z,red4); sy=blkred_sum(sy,red4); sx=blkred_sum(sx,red4);
  syy=blkred_sum(syy,red4); sxx=blkred_sum(sxx,red4);
  if (threadIdx.x==0){
    float invz=1.0f/z;
    float ey=sy*invz, ex=sx*invz;
    lossbn[bn]=(syy*invz-ey*ey)+(sxx*invz-ex*ex);
    float mu=s*(1.0f/PP), var=q*(1.0f/PP)-mu*mu;
    float A=rsqrtf(var+EPSN)*in1g[n];
    in1A[bn]=A; in1D[bn]=in1b[n]-mu*A;
  }
}

// ---------------- K12: centr_loss = mean(lossbn) ----------------
__global__ void k12_loss(const float* __restrict__ lossbn, float* __restrict__ lossout){
  int tid=threadIdx.x;   // 128 threads
  float v = lossbn[tid];
  #pragma unroll
  for (int off=32;off>0;off>>=1) v += __shfl_down(v,off,64);
  __shared__ float r2[2];
  if ((tid&63)==0) r2[tid>>6]=v;
  __syncthreads();
  if (tid==0) lossout[0] = (r2[0]+r2[1]) * (1.0f/128.0f);
}

// ---------------- K13: gen-block stage 1: g2 = c3.relu(IN1(msk)) + IN2 partials ----------------
__global__ void k13_gen1(const float* __restrict__ msk, const float* __restrict__ in1A,
                         const float* __restrict__ in1D, const float* __restrict__ c3w,
                         const float* __restrict__ c3b, float* __restrict__ g2,
                         float* __restrict__ in2s, float* __restrict__ in2q){
  int b = blockIdx.x/36; int pc = blockIdx.x - b*36;
  int p = pc*256+threadIdx.x;
  __shared__ float wsh[NCAP*NCAP];
  __shared__ float Ash[NCAP], Dsh[NCAP], bsh[NCAP];
  if (threadIdx.x < NCAP*NCAP) wsh[threadIdx.x] = c3w[threadIdx.x];
  if (threadIdx.x < NCAP){
    Ash[threadIdx.x]=in1A[b*NCAP+threadIdx.x];
    Dsh[threadIdx.x]=in1D[b*NCAP+threadIdx.x];
    bsh[threadIdx.x]=c3b[threadIdx.x];
  }
  __syncthreads();
  float h[NCAP];
  #pragma unroll
  for (int n=0;n<NCAP;n++)
    h[n] = fmaxf(0.f, Ash[n]*msk[(size_t)(b*NCAP+n)*PP+p] + Dsh[n]);
  float g[NCAP];
  #pragma unroll
  for (int o=0;o<NCAP;o++){
    float a = bsh[o];
    #pragma unroll
    for (int n=0;n<NCAP;n++) a += wsh[o*NCAP+n]*h[n];
    g[o]=a;
    g2[(size_t)(b*NCAP+o)*PP+p]=a;
  }
  int lane = threadIdx.x & 63;
  #pragma unroll
  for (int o=0;o<NCAP;o++){
    float a=g[o], q=g[o]*g[o];
    #pragma unroll
    for (int off=32;off>0;off>>=1){ a+=__shfl_down(a,off,64); q+=__shfl_down(q,off,64); }
    if (lane==0){ atomicAdd(&in2s[b*NCAP+o],a); atomicAdd(&in2q[b*NCAP+o],q); }
  }
}

// ---------------- K14: finalize IN2 affine ----------------
__global__ void k14_in2fin(const float* __restrict__ in2s, const float* __restrict__ in2q,
                           const float* __restrict__ g, const float* __restrict__ bb,
                           float* __restrict__ in2A, float* __restrict__ in2D){
  int i=threadIdx.x;   // 128 = b*16+o
  int o=i&15;
  float m=in2s[i]*(1.0f/PP), q=in2q[i]*(1.0f/PP);
  float A=rsqrtf(q-m*m+EPSN)*g[o];
  in2A[i]=A; in2D[i]=bb[o]-m*A;
}

// ---------------- K15: rec = sigmoid(c4.relu(IN2(g2))) ----------------
__global__ void k15_rec(const float* __restrict__ g2, const float* __restrict__ in2A,
                        const float* __restrict__ in2D, const float* __restrict__ c4w,
                        const float* __restrict__ c4b, float* __restrict__ rec){
  int b = blockIdx.x/36; int pc = blockIdx.x - b*36;
  int p = pc*256+threadIdx.x;
  __shared__ float wsh[3*NCAP], Ash[NCAP], Dsh[NCAP], bsh[3];
  if (threadIdx.x<3*NCAP) wsh[threadIdx.x]=c4w[threadIdx.x];
  if (threadIdx.x<NCAP){ Ash[threadIdx.x]=in2A[b*NCAP+threadIdx.x]; Dsh[threadIdx.x]=in2D[b*NCAP+threadIdx.x]; }
  if (threadIdx.x<3) bsh[threadIdx.x]=c4b[threadIdx.x];
  __syncthreads();
  float h[NCAP];
  #pragma unroll
  for (int o=0;o<NCAP;o++)
    h[o]=fmaxf(0.f, Ash[o]*g2[(size_t)(b*NCAP+o)*PP+p]+Dsh[o]);
  #pragma unroll
  for (int j=0;j<3;j++){
    float z=bsh[j];
    #pragma unroll
    for (int o=0;o<NCAP;o++) z += wsh[j*NCAP+o]*h[o];
    rec[(size_t)(b*3+j)*PP+p] = 1.0f/(1.0f+__expf(-z));
  }
}

// ---------------- K16: op_out[b,n,c,p] = op[b,n,c]*msk[b,n,p] ----------------
__global__ void k16_opout(const float* __restrict__ opv, const float* __restrict__ msk,
                          float* __restrict__ out){
  int bn = blockIdx.x / 9; int pt = blockIdx.x - bn*9;
  int base = pt*1024;
  __shared__ float ms[1024];
  __shared__ float opl[CC];
  for (int i=threadIdx.x;i<1024;i+=256) ms[i]=msk[(size_t)bn*PP+base+i];
  if (threadIdx.x<CC) opl[threadIdx.x]=opv[bn*CC+threadIdx.x];
  __syncthreads();
  float4 mv = ((const float4*)ms)[threadIdx.x];
  float* obase = out + (size_t)bn*CC*PP + base;
  #pragma unroll 4
  for (int c=0;c<CC;c++){
    float ov = opl[c];
    ((float4*)(obase + (size_t)c*PP))[threadIdx.x] = make_float4(ov*mv.x,ov*mv.y,ov*mv.z,ov*mv.w);
  }
}

// =======================================================================
extern "C" void kernel_launch(void* const* d_in, const int* in_sizes, int n_in,
                              void* d_out, int out_size, void* d_ws, size_t ws_size,
                              hipStream_t stream){
  const float* sr   = (const float*)d_in[0];
  const float* tg   = (const float*)d_in[1];
  const float* w_w  = (const float*)d_in[2];
  const float* w_b  = (const float*)d_in[3];
  const float* gn1g = (const float*)d_in[4];
  const float* gn1b = (const float*)d_in[5];
  const float* c1w  = (const float*)d_in[6];
  const float* c1b  = (const float*)d_in[7];
  const float* gn2g = (const float*)d_in[8];
  const float* gn2b = (const float*)d_in[9];
  const float* c2w  = (const float*)d_in[10];
  const float* c2b  = (const float*)d_in[11];
  const float* in1g = (const float*)d_in[12];
  const float* in1b = (const float*)d_in[13];
  const float* c3w  = (const float*)d_in[14];
  const float* c3b  = (const float*)d_in[15];
  const float* in2g = (const float*)d_in[16];
  const float* in2b = (const float*)d_in[17];
  const float* c4w  = (const float*)d_in[18];
  const float* c4b  = (const float*)d_in[19];
  float* out = (float*)d_out;
  float* ws  = (float*)d_ws;

  // workspace layout (floats) — byte-identical footprint to the proven round-0 layout
  float* t_   = ws + 0;
  float* S1   = ws + 512;
  float* S2   = ws + 1024;
  float* opv  = ws + 1536;
  float* uv   = ws + 9728;
  float* bu   = ws + 17920;
  float* mrow = ws + 18048;
  float* zrow = ws + 18176;
  float* rv   = ws + 18304;
  float* Aaff = ws + 26496;
  float* Daff = ws + 34688;
  float* gn2s = ws + 42880;
  float* gn2q = ws + 44928;
  float* A2   = ws + 46976;
  float* D2   = ws + 55168;
  float* in1A = ws + 63360;
  float* in1D = ws + 63488;
  float* lossbn = ws + 63616;
  float* in2s = ws + 63744;
  float* in2q = ws + 63872;
  float* in2A = ws + 64000;
  float* in2D = ws + 64128;
  float* dbuf = ws + 65536;              // 1,179,648 floats
  float* g2   = ws + 65536 + 1179648;    // 1,179,648 floats

  // d_out region reuse (everything here is overwritten by k16/mask/rec/etc later):
  unsigned short* y1b = (unsigned short*)d_out;                                  // 150,994,944 B
  unsigned short* tgt = (unsigned short*)((char*)d_out + 150994944);             // 9,437,184 B
  unsigned short* Wt  = (unsigned short*)((char*)d_out + 160432128);             // 73,728 B
  float* prt   = (float*)((char*)d_out + 160505856);                             // 2,359,296 B
  float* partm = (float*)((char*)d_out + 162865152);                             // 36,864 B
  float* partz = (float*)((char*)d_out + 162902016);                             // 36,864 B
  float* mskout  = out + 75497472;
  float* recout  = out + 76677120;
  float* lossout = out + 76898304;
  float* cofout  = out + 76898305;

  kpre_tgt<<<BB*36, 256, 0, stream>>>(tg, tgt);
  kw_bf16<<<144, 256, 0, stream>>>(c1w, Wt);
  k0_colstats<<<BB*CC, 256, 0, stream>>>(sr, tg, t_, S1, S2);
  k_update<<<BNN, 64, 0, stream>>>(w_w, w_b, t_, (float)PP, 1, opv, uv, bu);
  for (int it=0; it<3; ++it){
    k2f_dpass<<<BB*72, 128, 0, stream>>>(sr, uv, bu, dbuf, partm, partz, prt, it==2 ? 1 : 0);
    k3b_combine<<<BNN, 64, 0, stream>>>(partm, partz, mrow, zrow);
    k4c_combine<<<BNN, 64, 0, stream>>>(prt, partm, mrow, zrow, rv);
    k_update<<<BNN, 64, 0, stream>>>(w_w, w_b, rv, 1.0f, 0, opv, uv, bu);
  }
  k6_cofout<<<dim3(36, BNN), 256, 0, stream>>>(dbuf, mrow, zrow, cofout);
  k7_gn1<<<BNN, 64, 0, stream>>>(S1, S2, opv, gn1g, gn1b, Aaff, Daff, gn2s, gn2q, in2s, in2q);
  k8_conv1_mfma<<<BNN*36, 256, 0, stream>>>(tgt, Wt, c1b, Aaff, Daff, y1b, gn2s, gn2q);
  k9_gn2fin<<<BNN, 64, 0, stream>>>(gn2s, gn2q, gn2g, gn2b, A2, D2);
  k10_conv2<<<BNN*36, 256, 0, stream>>>(y1b, c2w, c2b, A2, D2, mskout);
  k11_mskstats<<<BNN, 256, 0, stream>>>(mskout, in1g, in1b, in1A, in1D, lossbn);
  k12_loss<<<1, 128, 0, stream>>>(lossbn, lossout);
  k13_gen1<<<BB*36, 256, 0, stream>>>(mskout, in1A, in1D, c3w, c3b, g2, in2s, in2q);
  k14_in2fin<<<1, 128, 0, stream>>>(in2s, in2q, in2g, in2b, in2A, in2D);
  k15_rec<<<BB*36, 256, 0, stream>>>(g2, in2A, in2D, c4w, c4b, recout);
  k16_opout<<<BNN*9, 256, 0, stream>>>(opv, mskout, out);
}